// Round 1
// baseline (2732.383 us; speedup 1.0000x reference)
//
#include <hip/hip_runtime.h>

#define N_USERS 100000
#define M_ITEMS 50000
#define N_TOTAL (N_USERS + M_ITEMS)
#define D 64
#define NNZ 4000000
#define BATCH 4096
#define LAYERS 3

// Concatenate user_emb and item_emb into emb buffer (float4-vectorized).
__global__ void init_emb_kernel(const float4* __restrict__ ue,
                                const float4* __restrict__ ie,
                                float4* __restrict__ emb) {
    size_t i = (size_t)blockIdx.x * blockDim.x + threadIdx.x;
    const size_t nu4  = (size_t)N_USERS * D / 4;
    const size_t tot4 = (size_t)N_TOTAL * D / 4;
    if (i >= tot4) return;
    emb[i] = (i < nu4) ? ue[i] : ie[i - nu4];
}

// Initialize the per-batch accumulators with the layer-0 embeddings.
__global__ void init_acc_kernel(const int* __restrict__ users,
                                const int* __restrict__ items,
                                const float* __restrict__ ue,
                                const float* __restrict__ ie,
                                float* __restrict__ u_acc,
                                float* __restrict__ i_acc) {
    int gid = blockIdx.x * blockDim.x + threadIdx.x;  // 2*BATCH*D threads
    int d = gid & (D - 1);
    int b = gid >> 6;
    if (b < BATCH) {
        u_acc[(size_t)b * D + d] = ue[(size_t)users[b] * D + d];
    } else if (b < 2 * BATCH) {
        int bb = b - BATCH;
        i_acc[(size_t)bb * D + d] = ie[(size_t)items[bb] * D + d];
    }
}

// One wave per nonzero; lane = dim. Gather coalesced, scatter via HW fp32 atomic.
__global__ void spmm_scatter_kernel(const int* __restrict__ rows,
                                    const int* __restrict__ cols,
                                    const float* __restrict__ vals,
                                    const float* __restrict__ emb_in,
                                    float* __restrict__ emb_out) {
    size_t gid = (size_t)blockIdx.x * blockDim.x + threadIdx.x;
    size_t e = gid >> 6;
    int d = (int)(gid & (D - 1));
    if (e >= NNZ) return;
    int r = rows[e];
    int c = cols[e];
    float v = vals[e];
    float x = emb_in[(size_t)c * D + d];
    unsafeAtomicAdd(&emb_out[(size_t)r * D + d], v * x);
}

// After each layer: pull this layer's emb at the 8192 interesting rows into accs.
__global__ void gather_acc_kernel(const int* __restrict__ users,
                                  const int* __restrict__ items,
                                  const float* __restrict__ emb,
                                  float* __restrict__ u_acc,
                                  float* __restrict__ i_acc) {
    int gid = blockIdx.x * blockDim.x + threadIdx.x;  // 2*BATCH*D threads
    int d = gid & (D - 1);
    int b = gid >> 6;
    if (b < BATCH) {
        u_acc[(size_t)b * D + d] += emb[(size_t)users[b] * D + d];
    } else if (b < 2 * BATCH) {
        int bb = b - BATCH;
        i_acc[(size_t)bb * D + d] += emb[((size_t)(N_USERS + items[bb])) * D + d];
    }
}

// One wave per batch element: dot(u_acc[b], i_acc[b]) / 16  (the /4 on each side).
__global__ void final_dot_kernel(const float* __restrict__ u_acc,
                                 const float* __restrict__ i_acc,
                                 float* __restrict__ out) {
    int gid = blockIdx.x * blockDim.x + threadIdx.x;
    int b = gid >> 6;
    int lane = gid & 63;
    if (b >= BATCH) return;
    float p = u_acc[(size_t)b * D + lane] * i_acc[(size_t)b * D + lane];
#pragma unroll
    for (int o = 32; o; o >>= 1) p += __shfl_xor(p, o, 64);
    if (lane == 0) out[b] = p * (1.0f / 16.0f);
}

extern "C" void kernel_launch(void* const* d_in, const int* in_sizes, int n_in,
                              void* d_out, int out_size, void* d_ws, size_t ws_size,
                              hipStream_t stream) {
    const int*   users = (const int*)d_in[0];
    const int*   items = (const int*)d_in[1];
    const float* ue    = (const float*)d_in[2];
    const float* ie    = (const float*)d_in[3];
    const int*   rows  = (const int*)d_in[4];
    const int*   cols  = (const int*)d_in[5];
    const float* vals  = (const float*)d_in[6];
    float*       out   = (float*)d_out;

    char* ws = (char*)d_ws;
    const size_t NB = (size_t)N_TOTAL * D * sizeof(float);  // 38.4 MB
    float* embA  = (float*)(ws);
    float* embB  = (float*)(ws + NB);
    float* u_acc = (float*)(ws + 2 * NB);
    float* i_acc = (float*)(ws + 2 * NB + (size_t)BATCH * D * sizeof(float));

    // Layer 0 init
    {
        size_t tot4 = (size_t)N_TOTAL * D / 4;
        init_emb_kernel<<<(unsigned)((tot4 + 255) / 256), 256, 0, stream>>>(
            (const float4*)ue, (const float4*)ie, (float4*)embA);
        init_acc_kernel<<<(2 * BATCH * D + 255) / 256, 256, 0, stream>>>(
            users, items, ue, ie, u_acc, i_acc);
    }

    float* cur = embA;
    float* nxt = embB;
    for (int l = 0; l < LAYERS; ++l) {
        hipMemsetAsync(nxt, 0, NB, stream);
        size_t threads = (size_t)NNZ * 64;
        spmm_scatter_kernel<<<(unsigned)((threads + 255) / 256), 256, 0, stream>>>(
            rows, cols, vals, cur, nxt);
        gather_acc_kernel<<<(2 * BATCH * D + 255) / 256, 256, 0, stream>>>(
            users, items, nxt, u_acc, i_acc);
        float* t = cur; cur = nxt; nxt = t;
    }

    final_dot_kernel<<<(BATCH * 64 + 255) / 256, 256, 0, stream>>>(u_acc, i_acc, out);
}

// Round 2
// 1361.883 us; speedup vs baseline: 2.0063x; 2.0063x over previous
//
#include <hip/hip_runtime.h>

#define N_USERS 100000
#define M_ITEMS 50000
#define N_TOTAL (N_USERS + M_ITEMS)
#define D 64
#define NNZ 4000000
#define BATCH 4096
#define LAYERS 3

// ---------------- init ----------------

__global__ void init_emb_kernel(const float4* __restrict__ ue,
                                const float4* __restrict__ ie,
                                float4* __restrict__ emb) {
    size_t i = (size_t)blockIdx.x * blockDim.x + threadIdx.x;
    const size_t nu4  = (size_t)N_USERS * D / 4;
    const size_t tot4 = (size_t)N_TOTAL * D / 4;
    if (i >= tot4) return;
    emb[i] = (i < nu4) ? ue[i] : ie[i - nu4];
}

__global__ void init_acc_kernel(const int* __restrict__ users,
                                const int* __restrict__ items,
                                const float* __restrict__ ue,
                                const float* __restrict__ ie,
                                float* __restrict__ u_acc,
                                float* __restrict__ i_acc) {
    int gid = blockIdx.x * blockDim.x + threadIdx.x;  // 2*BATCH*D threads
    int d = gid & (D - 1);
    int b = gid >> 6;
    if (b < BATCH) {
        u_acc[(size_t)b * D + d] = ue[(size_t)users[b] * D + d];
    } else if (b < 2 * BATCH) {
        int bb = b - BATCH;
        i_acc[(size_t)bb * D + d] = ie[(size_t)items[bb] * D + d];
    }
}

// ---------------- CSR build ----------------

__global__ void histogram_kernel(const int* __restrict__ rows,
                                 int* __restrict__ deg) {
    int e = blockIdx.x * blockDim.x + threadIdx.x;
    if (e < NNZ) atomicAdd(&deg[rows[e]], 1);
}

// Single-block exclusive scan over deg[N_TOTAL] -> row_start, cursor.
__global__ void scan_kernel(const int* __restrict__ deg,
                            int* __restrict__ row_start,
                            int* __restrict__ cursor) {
    __shared__ int partials[1024];
    const int t = threadIdx.x;
    const int chunk = (N_TOTAL + 1023) / 1024;
    const int lo = t * chunk;
    const int hi = (lo + chunk < N_TOTAL) ? lo + chunk : N_TOTAL;
    int s = 0;
    for (int i = lo; i < hi; ++i) s += deg[i];
    partials[t] = s;
    __syncthreads();
    // Hillis-Steele inclusive scan
    for (int off = 1; off < 1024; off <<= 1) {
        int v = (t >= off) ? partials[t - off] : 0;
        __syncthreads();
        partials[t] += v;
        __syncthreads();
    }
    int excl = (t == 0) ? 0 : partials[t - 1];
    for (int i = lo; i < hi; ++i) {
        row_start[i] = excl;
        cursor[i]    = excl;
        excl += deg[i];
    }
    if (t == 0) row_start[N_TOTAL] = NNZ;  // degrees always sum to NNZ
}

__global__ void scatter_kernel(const int* __restrict__ rows,
                               const int* __restrict__ cols,
                               const float* __restrict__ vals,
                               int* __restrict__ cursor,
                               int* __restrict__ sc,
                               float* __restrict__ sv) {
    int e = blockIdx.x * blockDim.x + threadIdx.x;
    if (e >= NNZ) return;
    int r = rows[e];
    int pos = atomicAdd(&cursor[r], 1);
    sc[pos] = cols[e];
    sv[pos] = vals[e];
}

// ---------------- CSR SpMM: one wave per row, lane = dim ----------------

__global__ void spmm_csr_kernel(const int* __restrict__ row_start,
                                const int* __restrict__ sc,
                                const float* __restrict__ sv,
                                const float* __restrict__ emb_in,
                                float* __restrict__ emb_out) {
    int wave = (blockIdx.x * blockDim.x + threadIdx.x) >> 6;
    int lane = threadIdx.x & 63;
    if (wave >= N_TOTAL) return;
    int s = row_start[wave];
    int e = row_start[wave + 1];
    float acc = 0.0f;
    for (int base = s; base < e; base += 64) {
        int n = e - base; if (n > 64) n = 64;
        int   c = 0; float v = 0.0f;
        if (base + lane < e) { c = sc[base + lane]; v = sv[base + lane]; }
        for (int j = 0; j < n; ++j) {
            int   cj = __shfl(c, j, 64);
            float vj = __shfl(v, j, 64);
            acc += vj * emb_in[(size_t)cj * D + lane];
        }
    }
    emb_out[(size_t)wave * D + lane] = acc;
}

// Layer-3: compute segment sums ONLY for the 8192 batch rows, add into accs.
__global__ void layer3_kernel(const int* __restrict__ users,
                              const int* __restrict__ items,
                              const int* __restrict__ row_start,
                              const int* __restrict__ sc,
                              const float* __restrict__ sv,
                              const float* __restrict__ emb_in,
                              float* __restrict__ u_acc,
                              float* __restrict__ i_acc) {
    int wave = (blockIdx.x * blockDim.x + threadIdx.x) >> 6;
    int lane = threadIdx.x & 63;
    if (wave >= 2 * BATCH) return;
    int row;
    float* dst;
    if (wave < BATCH) {
        row = users[wave];
        dst = &u_acc[(size_t)wave * D];
    } else {
        int bb = wave - BATCH;
        row = N_USERS + items[bb];
        dst = &i_acc[(size_t)bb * D];
    }
    int s = row_start[row];
    int e = row_start[row + 1];
    float acc = 0.0f;
    for (int base = s; base < e; base += 64) {
        int n = e - base; if (n > 64) n = 64;
        int   c = 0; float v = 0.0f;
        if (base + lane < e) { c = sc[base + lane]; v = sv[base + lane]; }
        for (int j = 0; j < n; ++j) {
            int   cj = __shfl(c, j, 64);
            float vj = __shfl(v, j, 64);
            acc += vj * emb_in[(size_t)cj * D + lane];
        }
    }
    dst[lane] += acc;
}

// After layers 1,2: pull emb rows at batch indices into accs.
__global__ void gather_acc_kernel(const int* __restrict__ users,
                                  const int* __restrict__ items,
                                  const float* __restrict__ emb,
                                  float* __restrict__ u_acc,
                                  float* __restrict__ i_acc) {
    int gid = blockIdx.x * blockDim.x + threadIdx.x;  // 2*BATCH*D threads
    int d = gid & (D - 1);
    int b = gid >> 6;
    if (b < BATCH) {
        u_acc[(size_t)b * D + d] += emb[(size_t)users[b] * D + d];
    } else if (b < 2 * BATCH) {
        int bb = b - BATCH;
        i_acc[(size_t)bb * D + d] += emb[((size_t)(N_USERS + items[bb])) * D + d];
    }
}

__global__ void final_dot_kernel(const float* __restrict__ u_acc,
                                 const float* __restrict__ i_acc,
                                 float* __restrict__ out) {
    int gid = blockIdx.x * blockDim.x + threadIdx.x;
    int b = gid >> 6;
    int lane = gid & 63;
    if (b >= BATCH) return;
    float p = u_acc[(size_t)b * D + lane] * i_acc[(size_t)b * D + lane];
#pragma unroll
    for (int o = 32; o; o >>= 1) p += __shfl_xor(p, o, 64);
    if (lane == 0) out[b] = p * (1.0f / 16.0f);
}

// ---------------- launch ----------------

extern "C" void kernel_launch(void* const* d_in, const int* in_sizes, int n_in,
                              void* d_out, int out_size, void* d_ws, size_t ws_size,
                              hipStream_t stream) {
    const int*   users = (const int*)d_in[0];
    const int*   items = (const int*)d_in[1];
    const float* ue    = (const float*)d_in[2];
    const float* ie    = (const float*)d_in[3];
    const int*   rows  = (const int*)d_in[4];
    const int*   cols  = (const int*)d_in[5];
    const float* vals  = (const float*)d_in[6];
    float*       out   = (float*)d_out;

    char* ws = (char*)d_ws;
    size_t off = 0;
    auto alloc = [&](size_t bytes) {
        void* p = ws + off;
        off += (bytes + 255) & ~(size_t)255;
        return p;
    };
    const size_t NB = (size_t)N_TOTAL * D * sizeof(float);   // 38.4 MB
    float* embA      = (float*)alloc(NB);
    float* embB      = (float*)alloc(NB);
    float* u_acc     = (float*)alloc((size_t)BATCH * D * sizeof(float));
    float* i_acc     = (float*)alloc((size_t)BATCH * D * sizeof(float));
    int*   deg       = (int*)alloc((size_t)N_TOTAL * sizeof(int));
    int*   row_start = (int*)alloc(((size_t)N_TOTAL + 1) * sizeof(int));
    int*   cursor    = (int*)alloc((size_t)N_TOTAL * sizeof(int));
    int*   sc        = (int*)alloc((size_t)NNZ * sizeof(int));
    float* sv        = (float*)alloc((size_t)NNZ * sizeof(float));

    // init
    {
        size_t tot4 = (size_t)N_TOTAL * D / 4;
        init_emb_kernel<<<(unsigned)((tot4 + 255) / 256), 256, 0, stream>>>(
            (const float4*)ue, (const float4*)ie, (float4*)embA);
        init_acc_kernel<<<(2 * BATCH * D + 255) / 256, 256, 0, stream>>>(
            users, items, ue, ie, u_acc, i_acc);
    }

    // CSR build
    hipMemsetAsync(deg, 0, (size_t)N_TOTAL * sizeof(int), stream);
    histogram_kernel<<<(NNZ + 255) / 256, 256, 0, stream>>>(rows, deg);
    scan_kernel<<<1, 1024, 0, stream>>>(deg, row_start, cursor);
    scatter_kernel<<<(NNZ + 255) / 256, 256, 0, stream>>>(rows, cols, vals, cursor, sc, sv);

    // Layer 1: embA -> embB
    {
        int waves = N_TOTAL;
        spmm_csr_kernel<<<(waves * 64 + 255) / 256, 256, 0, stream>>>(
            row_start, sc, sv, embA, embB);
        gather_acc_kernel<<<(2 * BATCH * D + 255) / 256, 256, 0, stream>>>(
            users, items, embB, u_acc, i_acc);
    }
    // Layer 2: embB -> embA
    {
        int waves = N_TOTAL;
        spmm_csr_kernel<<<(waves * 64 + 255) / 256, 256, 0, stream>>>(
            row_start, sc, sv, embB, embA);
        gather_acc_kernel<<<(2 * BATCH * D + 255) / 256, 256, 0, stream>>>(
            users, items, embA, u_acc, i_acc);
    }
    // Layer 3: only the 8192 batch rows, straight into accs
    layer3_kernel<<<(2 * BATCH * 64 + 255) / 256, 256, 0, stream>>>(
        users, items, row_start, sc, sv, embA, u_acc, i_acc);

    final_dot_kernel<<<(BATCH * 64 + 255) / 256, 256, 0, stream>>>(u_acc, i_acc, out);
}

// Round 3
// 1019.215 us; speedup vs baseline: 2.6809x; 1.3362x over previous
//
#include <hip/hip_runtime.h>

#define N_USERS 100000
#define M_ITEMS 50000
#define N_TOTAL (N_USERS + M_ITEMS)
#define D 64
#define NNZ 4000000
#define BATCH 4096
#define LAYERS 3

#define SCAN_CHUNK 1024
#define SCAN_BLOCKS ((N_TOTAL + SCAN_CHUNK - 1) / SCAN_CHUNK)  // 147

// ---------------- init ----------------

__global__ void init_emb_kernel(const float4* __restrict__ ue,
                                const float4* __restrict__ ie,
                                float4* __restrict__ emb) {
    size_t i = (size_t)blockIdx.x * blockDim.x + threadIdx.x;
    const size_t nu4  = (size_t)N_USERS * D / 4;
    const size_t tot4 = (size_t)N_TOTAL * D / 4;
    if (i >= tot4) return;
    emb[i] = (i < nu4) ? ue[i] : ie[i - nu4];
}

__global__ void init_acc_kernel(const int* __restrict__ users,
                                const int* __restrict__ items,
                                const float* __restrict__ ue,
                                const float* __restrict__ ie,
                                float* __restrict__ u_acc,
                                float* __restrict__ i_acc) {
    int gid = blockIdx.x * blockDim.x + threadIdx.x;  // 2*BATCH*D threads
    int d = gid & (D - 1);
    int b = gid >> 6;
    if (b < BATCH) {
        u_acc[(size_t)b * D + d] = ue[(size_t)users[b] * D + d];
    } else if (b < 2 * BATCH) {
        int bb = b - BATCH;
        i_acc[(size_t)bb * D + d] = ie[(size_t)items[bb] * D + d];
    }
}

// ---------------- CSR build ----------------

__global__ void histogram_kernel(const int* __restrict__ rows,
                                 int* __restrict__ deg) {
    int e = blockIdx.x * blockDim.x + threadIdx.x;
    if (e < NNZ) atomicAdd(&deg[rows[e]], 1);
}

// Phase A: per-block sums of deg (1024 elements per 256-thread block).
__global__ void scan_blocksum_kernel(const int* __restrict__ deg,
                                     int* __restrict__ blocksum) {
    __shared__ int lds[4];
    int t = threadIdx.x;
    int base = blockIdx.x * SCAN_CHUNK;
    int s = 0;
#pragma unroll
    for (int k = 0; k < 4; ++k) {
        int i = base + t + k * 256;
        if (i < N_TOTAL) s += deg[i];
    }
#pragma unroll
    for (int o = 32; o; o >>= 1) s += __shfl_xor(s, o, 64);
    if ((t & 63) == 0) lds[t >> 6] = s;
    __syncthreads();
    if (t == 0) blocksum[blockIdx.x] = lds[0] + lds[1] + lds[2] + lds[3];
}

// Phase B: single small block scans the 147 block sums (exclusive).
__global__ void scan_blockoff_kernel(const int* __restrict__ blocksum,
                                     int* __restrict__ blockoff) {
    __shared__ int lds[256];
    int t = threadIdx.x;
    lds[t] = (t < SCAN_BLOCKS) ? blocksum[t] : 0;
    __syncthreads();
    for (int off = 1; off < 256; off <<= 1) {
        int v = (t >= off) ? lds[t - off] : 0;
        __syncthreads();
        lds[t] += v;
        __syncthreads();
    }
    if (t < SCAN_BLOCKS) blockoff[t] = (t == 0) ? 0 : lds[t - 1];
}

// Phase C: per-block exclusive scan of 1024 deg elements + blockoff;
// write row_start and cursor.
__global__ void scan_write_kernel(const int* __restrict__ deg,
                                  const int* __restrict__ blockoff,
                                  int* __restrict__ row_start,
                                  int* __restrict__ cursor) {
    __shared__ int wsum[16];   // 1024 threads = 16 waves
    int t = threadIdx.x;       // 0..1023
    int lane = t & 63;
    int wid = t >> 6;
    int i = blockIdx.x * SCAN_CHUNK + t;
    int x = (i < N_TOTAL) ? deg[i] : 0;
    // wave-inclusive scan
    int inc = x;
#pragma unroll
    for (int o = 1; o < 64; o <<= 1) {
        int v = __shfl_up(inc, o, 64);
        if (lane >= o) inc += v;
    }
    if (lane == 63) wsum[wid] = inc;
    __syncthreads();
    if (wid == 0) {
        int ws = (lane < 16) ? wsum[lane] : 0;
#pragma unroll
        for (int o = 1; o < 16; o <<= 1) {
            int v = __shfl_up(ws, o, 64);
            if (lane >= o) ws += v;
        }
        if (lane < 16) wsum[lane] = ws;
    }
    __syncthreads();
    int waveoff = (wid == 0) ? 0 : wsum[wid - 1];
    int excl = blockoff[blockIdx.x] + waveoff + (inc - x);
    if (i < N_TOTAL) {
        row_start[i] = excl;
        cursor[i]    = excl;
    }
    if (blockIdx.x == 0 && t == 0) row_start[N_TOTAL] = NNZ;
}

// Scatter edges into CSR order as packed int2 {col, bitcast(val)}.
__global__ void scatter_kernel(const int* __restrict__ rows,
                               const int* __restrict__ cols,
                               const float* __restrict__ vals,
                               int* __restrict__ cursor,
                               int2* __restrict__ edges) {
    int e = blockIdx.x * blockDim.x + threadIdx.x;
    if (e >= NNZ) return;
    int r = rows[e];
    int pos = atomicAdd(&cursor[r], 1);
    edges[pos] = make_int2(cols[e], __float_as_int(vals[e]));
}

// ---------------- CSR SpMM: one wave per row, lane = dim ----------------

__global__ void spmm_csr_kernel(const int* __restrict__ row_start,
                                const int2* __restrict__ edges,
                                const float* __restrict__ emb_in,
                                float* __restrict__ emb_out) {
    int wave = (blockIdx.x * blockDim.x + threadIdx.x) >> 6;
    int lane = threadIdx.x & 63;
    if (wave >= N_TOTAL) return;
    int s = row_start[wave];
    int e = row_start[wave + 1];
    float acc = 0.0f;
    for (int base = s; base < e; base += 64) {
        int n = e - base; if (n > 64) n = 64;
        int c = 0; float v = 0.0f;
        if (base + lane < e) {
            int2 ev = edges[base + lane];
            c = ev.x;
            v = __int_as_float(ev.y);
        }
        for (int j = 0; j < n; ++j) {
            int   cj = __shfl(c, j, 64);
            float vj = __shfl(v, j, 64);
            acc += vj * emb_in[(size_t)cj * D + lane];
        }
    }
    emb_out[(size_t)wave * D + lane] = acc;
}

// Layer-3: segment sums ONLY for the 8192 batch rows, added into accs.
__global__ void layer3_kernel(const int* __restrict__ users,
                              const int* __restrict__ items,
                              const int* __restrict__ row_start,
                              const int2* __restrict__ edges,
                              const float* __restrict__ emb_in,
                              float* __restrict__ u_acc,
                              float* __restrict__ i_acc) {
    int wave = (blockIdx.x * blockDim.x + threadIdx.x) >> 6;
    int lane = threadIdx.x & 63;
    if (wave >= 2 * BATCH) return;
    int row;
    float* dst;
    if (wave < BATCH) {
        row = users[wave];
        dst = &u_acc[(size_t)wave * D];
    } else {
        int bb = wave - BATCH;
        row = N_USERS + items[bb];
        dst = &i_acc[(size_t)bb * D];
    }
    int s = row_start[row];
    int e = row_start[row + 1];
    float acc = 0.0f;
    for (int base = s; base < e; base += 64) {
        int n = e - base; if (n > 64) n = 64;
        int c = 0; float v = 0.0f;
        if (base + lane < e) {
            int2 ev = edges[base + lane];
            c = ev.x;
            v = __int_as_float(ev.y);
        }
        for (int j = 0; j < n; ++j) {
            int   cj = __shfl(c, j, 64);
            float vj = __shfl(v, j, 64);
            acc += vj * emb_in[(size_t)cj * D + lane];
        }
    }
    dst[lane] += acc;
}

// After layers 1,2: pull emb rows at batch indices into accs.
__global__ void gather_acc_kernel(const int* __restrict__ users,
                                  const int* __restrict__ items,
                                  const float* __restrict__ emb,
                                  float* __restrict__ u_acc,
                                  float* __restrict__ i_acc) {
    int gid = blockIdx.x * blockDim.x + threadIdx.x;  // 2*BATCH*D threads
    int d = gid & (D - 1);
    int b = gid >> 6;
    if (b < BATCH) {
        u_acc[(size_t)b * D + d] += emb[(size_t)users[b] * D + d];
    } else if (b < 2 * BATCH) {
        int bb = b - BATCH;
        i_acc[(size_t)bb * D + d] += emb[((size_t)(N_USERS + items[bb])) * D + d];
    }
}

__global__ void final_dot_kernel(const float* __restrict__ u_acc,
                                 const float* __restrict__ i_acc,
                                 float* __restrict__ out) {
    int gid = blockIdx.x * blockDim.x + threadIdx.x;
    int b = gid >> 6;
    int lane = gid & 63;
    if (b >= BATCH) return;
    float p = u_acc[(size_t)b * D + lane] * i_acc[(size_t)b * D + lane];
#pragma unroll
    for (int o = 32; o; o >>= 1) p += __shfl_xor(p, o, 64);
    if (lane == 0) out[b] = p * (1.0f / 16.0f);
}

// ---------------- launch ----------------

extern "C" void kernel_launch(void* const* d_in, const int* in_sizes, int n_in,
                              void* d_out, int out_size, void* d_ws, size_t ws_size,
                              hipStream_t stream) {
    const int*   users = (const int*)d_in[0];
    const int*   items = (const int*)d_in[1];
    const float* ue    = (const float*)d_in[2];
    const float* ie    = (const float*)d_in[3];
    const int*   rows  = (const int*)d_in[4];
    const int*   cols  = (const int*)d_in[5];
    const float* vals  = (const float*)d_in[6];
    float*       out   = (float*)d_out;

    char* ws = (char*)d_ws;
    size_t off = 0;
    auto alloc = [&](size_t bytes) {
        void* p = ws + off;
        off += (bytes + 255) & ~(size_t)255;
        return p;
    };
    const size_t NB = (size_t)N_TOTAL * D * sizeof(float);   // 38.4 MB
    float* embA      = (float*)alloc(NB);
    float* embB      = (float*)alloc(NB);
    float* u_acc     = (float*)alloc((size_t)BATCH * D * sizeof(float));
    float* i_acc     = (float*)alloc((size_t)BATCH * D * sizeof(float));
    int*   deg       = (int*)alloc((size_t)N_TOTAL * sizeof(int));
    int*   row_start = (int*)alloc(((size_t)N_TOTAL + 1) * sizeof(int));
    int*   cursor    = (int*)alloc((size_t)N_TOTAL * sizeof(int));
    int*   blocksum  = (int*)alloc((size_t)SCAN_BLOCKS * sizeof(int));
    int*   blockoff  = (int*)alloc((size_t)SCAN_BLOCKS * sizeof(int));
    int2*  edges     = (int2*)alloc((size_t)NNZ * sizeof(int2));

    // init
    {
        size_t tot4 = (size_t)N_TOTAL * D / 4;
        init_emb_kernel<<<(unsigned)((tot4 + 255) / 256), 256, 0, stream>>>(
            (const float4*)ue, (const float4*)ie, (float4*)embA);
        init_acc_kernel<<<(2 * BATCH * D + 255) / 256, 256, 0, stream>>>(
            users, items, ue, ie, u_acc, i_acc);
    }

    // CSR build
    hipMemsetAsync(deg, 0, (size_t)N_TOTAL * sizeof(int), stream);
    histogram_kernel<<<(NNZ + 255) / 256, 256, 0, stream>>>(rows, deg);
    scan_blocksum_kernel<<<SCAN_BLOCKS, 256, 0, stream>>>(deg, blocksum);
    scan_blockoff_kernel<<<1, 256, 0, stream>>>(blocksum, blockoff);
    scan_write_kernel<<<SCAN_BLOCKS, 1024, 0, stream>>>(deg, blockoff, row_start, cursor);
    scatter_kernel<<<(NNZ + 255) / 256, 256, 0, stream>>>(rows, cols, vals, cursor, edges);

    // Layer 1: embA -> embB
    spmm_csr_kernel<<<(N_TOTAL * 64 + 255) / 256, 256, 0, stream>>>(
        row_start, edges, embA, embB);
    gather_acc_kernel<<<(2 * BATCH * D + 255) / 256, 256, 0, stream>>>(
        users, items, embB, u_acc, i_acc);

    // Layer 2: embB -> embA
    spmm_csr_kernel<<<(N_TOTAL * 64 + 255) / 256, 256, 0, stream>>>(
        row_start, edges, embB, embA);
    gather_acc_kernel<<<(2 * BATCH * D + 255) / 256, 256, 0, stream>>>(
        users, items, embA, u_acc, i_acc);

    // Layer 3: only the 8192 batch rows, straight into accs
    layer3_kernel<<<(2 * BATCH * 64 + 255) / 256, 256, 0, stream>>>(
        users, items, row_start, edges, embA, u_acc, i_acc);

    final_dot_kernel<<<(BATCH * 64 + 255) / 256, 256, 0, stream>>>(u_acc, i_acc, out);
}